// Round 7
// baseline (401.397 us; speedup 1.0000x reference)
//
#include <hip/hip_runtime.h>

#define HC 128          // H*C = output dim
#define HEADS 8
#define CPH 16
#define EDIM 16
#define NG 8
#define GEPS 1e-5f
#define LOG2E 1.44269504f

typedef float f32x2 __attribute__((ext_vector_type(2)));

// ---------- 8-lane (head) sum via DPP: half_mirror + quad_perm xor2/xor1 ----------
__device__ __forceinline__ float head8_sum(float p) {
  int t;
  t = __builtin_amdgcn_update_dpp(0, __float_as_int(p), 0x141, 0xF, 0xF, true); // row_half_mirror
  p += __int_as_float(t);
  t = __builtin_amdgcn_update_dpp(0, __float_as_int(p), 0x4E, 0xF, 0xF, true);  // quad_perm [2,3,0,1]
  p += __int_as_float(t);
  t = __builtin_amdgcn_update_dpp(0, __float_as_int(p), 0xB1, 0xF, 0xF, true);  // quad_perm [1,0,3,2]
  p += __int_as_float(t);
  return p;
}

// ---------- K0: zero scratch ----------
__global__ void zero_k(float* __restrict__ p, size_t nwords) {
  size_t i = (size_t)blockIdx.x * 256 + threadIdx.x;
  if (i < nwords) p[i] = 0.f;
}

// ---------- K1: degree of real edges (by dst) + group-boundary marks ----------
__global__ void count_deg_mark(const int* __restrict__ ei, int* __restrict__ deg,
                               const int* __restrict__ batch, int* __restrict__ genc,
                               int E, int N) {
  int e = blockIdx.x * 256 + threadIdx.x;
  if (e >= E) return;
  atomicAdd(&deg[ei[E + e]], 1);
  if (e < N && (e == 0 || batch[e] != batch[e - 1])) {
    // encode start index i as (N - i) so zero-init means "empty group"
    atomicMax(&genc[batch[e]], N - e);
  }
}

// ---------- K2: xl = x@Wl+bl, xr = x@Wr+br — LDS-tiled GEMM, all-LDS inner loop ----
#define GEMM_ROWS 32
__global__ void __launch_bounds__(256) gemm_tiled(
    const float* __restrict__ x,
    const float* __restrict__ Wl, const float* __restrict__ bl,
    const float* __restrict__ Wr, const float* __restrict__ br,
    float* __restrict__ xl, float* __restrict__ xr, int N) {
  __shared__ float4 WL[32][32];   // [k within chunk][col float4 group] 16KB
  __shared__ float4 WR[32][32];   // 16KB
  __shared__ float4 XS[GEMM_ROWS][8];  // [local row][k4 within chunk] 4KB
  int t = threadIdx.x;
  int cg = t & 31;                // col float4 group (0..31)
  int rt = t >> 5;                // row-thread (0..7), owns rows rt*4..rt*4+3
  int row0 = blockIdx.x * GEMM_ROWS;
  float4 bl4 = ((const float4*)bl)[cg];
  float4 br4 = ((const float4*)br)[cg];
  float4 accl[4], accr[4];
  #pragma unroll
  for (int r = 0; r < 4; ++r) { accl[r] = bl4; accr[r] = br4; }
  const float4* Wl4 = (const float4*)Wl;
  const float4* Wr4 = (const float4*)Wr;
  const float4* x4  = (const float4*)x;
  int srow = t >> 3, sk4 = t & 7;
  long sgrow = row0 + srow;
  for (int kc = 0; kc < 4; ++kc) {
    __syncthreads();              // previous chunk fully consumed
    #pragma unroll
    for (int i = 0; i < 4; ++i) {
      int idx = t + i * 256;      // 0..1023
      int kr = idx >> 5, gg = idx & 31;
      WL[kr][gg] = Wl4[(kc * 32 + kr) * 32 + gg];
      WR[kr][gg] = Wr4[(kc * 32 + kr) * 32 + gg];
    }
    XS[srow][sk4] = (sgrow < N) ? x4[sgrow * 32 + kc * 8 + sk4]
                                : make_float4(0.f, 0.f, 0.f, 0.f);
    __syncthreads();
    #pragma unroll
    for (int k4 = 0; k4 < 8; ++k4) {
      float4 xv[4];
      #pragma unroll
      for (int r = 0; r < 4; ++r) xv[r] = XS[rt * 4 + r][k4];
      #pragma unroll
      for (int kk = 0; kk < 4; ++kk) {
        float4 wl = WL[k4 * 4 + kk][cg];
        float4 wr = WR[k4 * 4 + kk][cg];
        #pragma unroll
        for (int r = 0; r < 4; ++r) {
          float xs = (&xv[r].x)[kk];
          accl[r].x = fmaf(xs, wl.x, accl[r].x);
          accl[r].y = fmaf(xs, wl.y, accl[r].y);
          accl[r].z = fmaf(xs, wl.z, accl[r].z);
          accl[r].w = fmaf(xs, wl.w, accl[r].w);
          accr[r].x = fmaf(xs, wr.x, accr[r].x);
          accr[r].y = fmaf(xs, wr.y, accr[r].y);
          accr[r].z = fmaf(xs, wr.z, accr[r].z);
          accr[r].w = fmaf(xs, wr.w, accr[r].w);
        }
      }
    }
  }
  #pragma unroll
  for (int r = 0; r < 4; ++r) {
    long row = row0 + rt * 4 + r;
    if (row < N) {
      ((float4*)(xl + row * HC))[cg] = accl[r];
      ((float4*)(xr + row * HC))[cg] = accr[r];
    }
  }
}

// ---------- K3: scan of deg -> offsets (CSR) ----------
__global__ void scan1(const int* __restrict__ deg, int* __restrict__ bsum, int N) {
  __shared__ int s[256];
  int t = threadIdx.x;
  int n = blockIdx.x * 256 + t;
  s[t] = (n < N) ? deg[n] : 0;
  __syncthreads();
  for (int off = 128; off > 0; off >>= 1) {
    if (t < off) s[t] += s[t + off];
    __syncthreads();
  }
  if (t == 0) bsum[blockIdx.x] = s[0];
}
__global__ void scan2(const int* __restrict__ bsum, int* __restrict__ bofs, int nb,
                      int* __restrict__ offsets, int N,
                      const int* __restrict__ genc, int* __restrict__ gstart) {
  int run = 0;
  for (int b = 0; b < nb; ++b) { bofs[b] = run; run += bsum[b]; }
  offsets[N] = run;
  // decode group starts; suffix-min so empty groups collapse to 0-length
  int nxt = N;
  gstart[NG] = N;
  for (int g = NG - 1; g >= 0; --g) {
    int st = N - genc[g];
    if (st > nxt) st = nxt;
    gstart[g] = st;
    nxt = st;
  }
}
__global__ void scan3(const int* __restrict__ deg, const int* __restrict__ bofs,
                      int* __restrict__ offsets, int N) {
  __shared__ int s[256];
  int t = threadIdx.x;
  int n = blockIdx.x * 256 + t;
  int v = (n < N) ? deg[n] : 0;
  s[t] = v;
  __syncthreads();
  for (int off = 1; off < 256; off <<= 1) {
    int add = (t >= off) ? s[t - off] : 0;
    __syncthreads();
    s[t] += add;
    __syncthreads();
  }
  if (n < N) offsets[n] = bofs[blockIdx.x] + s[t] - v;  // exclusive
}

// ---------- K4: fill CSR with (edge, src) pairs; consumes deg ----------
__global__ void fill_csr(const int* __restrict__ ei, int* __restrict__ deg,
                         const int* __restrict__ offsets, int2* __restrict__ csr2, int E) {
  int e = blockIdx.x * 256 + threadIdx.x;
  if (e >= E) return;
  int d = ei[E + e];
  int pos = atomicSub(&deg[d], 1) - 1;
  csr2[offsets[d] + pos] = make_int2(e, ei[e]);
}

// ---------- K5: FUSED per-node attention + defer-max online softmax + agg ----------
// ONE WAVE per destination node; lane l owns channels (2l, 2l+1) as packed f32x2
// (v_pk_fma_f32 full-rate packed fp32). 256-thr block = 4 independent waves =
// 4 nodes, no barriers. Head = 8 lanes -> 3-stage DPP reduce. Self-loop
// (ea fill 'mean') merged at the end via linearity of the ea.We dot.
// Logits in log2 space (att pre-scaled by log2e) so exp == v_exp_f32.
__global__ void __launch_bounds__(256) fused_node(
    const int* __restrict__ offsets, const int2* __restrict__ csr2,
    const float* __restrict__ ea,
    const float* __restrict__ xl, const float* __restrict__ xr,
    const float* __restrict__ We, const float* __restrict__ att,
    const float* __restrict__ x, const float* __restrict__ bias,
    float* __restrict__ out, int N) {
  int l = threadIdx.x & 63;
  long n = (long)blockIdx.x * 4 + (threadIdx.x >> 6);
  if (n >= N) return;
  int c0 = l * 2;
  // We pairs, k-major: wx[kp] = (We[2kp][c0], We[2kp+1][c0]); wy for c0+1.
  f32x2 wx[8], wy[8];
  #pragma unroll
  for (int kp = 0; kp < 8; ++kp) {
    wx[kp] = (f32x2){We[(2 * kp) * HC + c0],     We[(2 * kp + 1) * HC + c0]};
    wy[kp] = (f32x2){We[(2 * kp) * HC + c0 + 1], We[(2 * kp + 1) * HC + c0 + 1]};
  }
  f32x2 av2 = {att[c0] * LOG2E, att[c0 + 1] * LOG2E};
  f32x2 av08 = 0.8f * av2, av02 = 0.2f * av2;
  f32x2 xl2 = *(const f32x2*)(xl + n * HC + c0);
  f32x2 xr2 = *(const f32x2*)(xr + n * HC + c0);
  f32x2 seedA = {xr2.x, 0.f};   // dot-accumulator seeds (fold +xr into hadd)
  f32x2 seedB = {xr2.y, 0.f};
  int j0 = offsets[n], j1 = offsets[n + 1];

  float m = -INFINITY;          // running max (log2), uniform per 8-lane head
  float den = 0.f;
  f32x2 acc = {0.f, 0.f};
  f32x2 eesum = {0.f, 0.f};     // per-channel sum of (eev + xr); adjusted at end

  auto edge_update = [&](int e, f32x2 xls) {
    const float4* eap = (const float4*)(ea + (long)e * EDIM);
    float4 a0 = eap[0], a1 = eap[1], a2 = eap[2], a3 = eap[3];
    f32x2 dA = seedA, dB = seedB;
    f32x2 e01;
    e01 = (f32x2){a0.x, a0.y};
    dA = __builtin_elementwise_fma(e01, wx[0], dA);
    dB = __builtin_elementwise_fma(e01, wy[0], dB);
    e01 = (f32x2){a0.z, a0.w};
    dA = __builtin_elementwise_fma(e01, wx[1], dA);
    dB = __builtin_elementwise_fma(e01, wy[1], dB);
    e01 = (f32x2){a1.x, a1.y};
    dA = __builtin_elementwise_fma(e01, wx[2], dA);
    dB = __builtin_elementwise_fma(e01, wy[2], dB);
    e01 = (f32x2){a1.z, a1.w};
    dA = __builtin_elementwise_fma(e01, wx[3], dA);
    dB = __builtin_elementwise_fma(e01, wy[3], dB);
    e01 = (f32x2){a2.x, a2.y};
    dA = __builtin_elementwise_fma(e01, wx[4], dA);
    dB = __builtin_elementwise_fma(e01, wy[4], dB);
    e01 = (f32x2){a2.z, a2.w};
    dA = __builtin_elementwise_fma(e01, wx[5], dA);
    dB = __builtin_elementwise_fma(e01, wy[5], dB);
    e01 = (f32x2){a3.x, a3.y};
    dA = __builtin_elementwise_fma(e01, wx[6], dA);
    dB = __builtin_elementwise_fma(e01, wy[6], dB);
    e01 = (f32x2){a3.z, a3.w};
    dA = __builtin_elementwise_fma(e01, wx[7], dA);
    dB = __builtin_elementwise_fma(e01, wy[7], dB);
    f32x2 mm = {dA.x + dA.y, dB.x + dB.y};   // = eev + xr (per channel)
    eesum += mm;
    mm += xls;
    f32x2 t = __builtin_elementwise_fma(
        av08, __builtin_elementwise_max(mm, (f32x2)0.f), av02 * mm);
    float p = head8_sum(t.x + t.y);    // head logit, uniform in 8-lane group
    if (p > m + 11.5f) {               // rare: new max grew past threshold
      float sc = exp2f(m - p);
      acc = acc * sc + xls;
      den = fmaf(den, sc, 1.f);
      m = p;
    } else {                           // common: single exp2, no rescale
      float w = exp2f(p - m);
      acc = __builtin_elementwise_fma((f32x2)w, xls, acc);
      den += w;
    }
  };

  int j = j0;
  if ((j & 1) && j < j1) {             // peel to 16B-aligned pair boundary
    int2 es = csr2[j];
    int e = __builtin_amdgcn_readfirstlane(es.x);
    int s = __builtin_amdgcn_readfirstlane(es.y);
    edge_update(e, *(const f32x2*)(xl + (long)s * HC + c0));
    ++j;
  }
  for (; j + 1 < j1; j += 2) {
    int4 q = *(const int4*)(csr2 + j);  // two (edge,src) pairs, one dwordx4
    int e0 = __builtin_amdgcn_readfirstlane(q.x);
    int s0 = __builtin_amdgcn_readfirstlane(q.y);
    int e1 = __builtin_amdgcn_readfirstlane(q.z);
    int s1 = __builtin_amdgcn_readfirstlane(q.w);
    f32x2 xls0 = *(const f32x2*)(xl + (long)s0 * HC + c0);
    f32x2 xls1 = *(const f32x2*)(xl + (long)s1 * HC + c0);
    edge_update(e0, xls0);
    edge_update(e1, xls1);
  }
  if (j < j1) {
    int2 es = csr2[j];
    int e = __builtin_amdgcn_readfirstlane(es.x);
    int s = __builtin_amdgcn_readfirstlane(es.y);
    edge_update(e, *(const f32x2*)(xl + (long)s * HC + c0));
  }

  // ---- self-loop ----
  int dg = j1 - j0;
  f32x2 ee = (dg > 0) ? (eesum * (1.f / (float)dg) - xr2) : (f32x2)0.f;
  f32x2 mm = xl2 + xr2 + ee;
  f32x2 t = __builtin_elementwise_fma(
      av08, __builtin_elementwise_max(mm, (f32x2)0.f), av02 * mm);
  float p = head8_sum(t.x + t.y);
  if (p > m) {
    float sc = exp2f(m - p);
    acc = acc * sc + xl2;
    den = fmaf(den, sc, 1.f);
  } else {
    float w = exp2f(p - m);
    acc = __builtin_elementwise_fma((f32x2)w, xl2, acc);
    den += w;
  }

  f32x2 b2 = *(const f32x2*)(bias + c0);
  f32x2 x2 = *(const f32x2*)(x + n * HC + c0);
  f32x2 o = acc * (1.f / den) + b2 + x2;
  *(f32x2*)(out + n * HC + c0) = o;
}

// ---------- K6: GraphNorm segment sums (grid-parallel over group slices) ----------
#define GN_SLICES 32
__global__ void __launch_bounds__(128) gn_stats(
    const float* __restrict__ out, const int* __restrict__ gstart,
    float* __restrict__ gsum, float* __restrict__ gsq) {
  int g = blockIdx.x >> 5;
  int slice = blockIdx.x & 31;
  int s0 = gstart[g], s1 = gstart[g + 1];
  int cnt = s1 - s0;
  if (cnt <= 0) return;
  int chunk = (cnt + GN_SLICES - 1) / GN_SLICES;
  int lo = s0 + slice * chunk;
  int hi = lo + chunk; if (hi > s1) hi = s1;
  if (lo >= hi) return;
  int ch = threadIdx.x;
  float sum = 0.f, sq = 0.f;
  for (int nrow = lo; nrow < hi; ++nrow) {
    float v = out[(long)nrow * HC + ch];
    sum += v; sq += v * v;
  }
  atomicAdd(&gsum[g * HC + ch], sum);
  atomicAdd(&gsq[g * HC + ch], sq);
}

// ---------- K7: finalize mean / inv-std ----------
__global__ void gn_finalize(const float* __restrict__ gsum, const float* __restrict__ gsq,
                            const int* __restrict__ gstart, const float* __restrict__ gms,
                            float* __restrict__ msub, float* __restrict__ istd) {
  int t = blockIdx.x * 256 + threadIdx.x;
  if (t >= NG * HC) return;
  int g = t >> 7, ch = t & 127;
  float cnt = (float)(gstart[g + 1] - gstart[g]);
  if (cnt < 1.f) cnt = 1.f;
  float mean = gsum[t] / cnt;
  float c = gms[ch] * mean;              // the subtracted constant
  float ex2 = gsq[t] / cnt;
  float var = ex2 - 2.f * c * mean + c * c;   // E[(x-c)^2]
  msub[t] = c;
  istd[t] = rsqrtf(var + GEPS);
}

// ---------- K8: normalize + affine + ELU (float4) ----------
__global__ void gn_apply(float* __restrict__ out, const int* __restrict__ batch,
                         const float* __restrict__ msub, const float* __restrict__ istd,
                         const float* __restrict__ gnw, const float* __restrict__ gnb, int N) {
  long i = (long)blockIdx.x * 256 + threadIdx.x;     // float4 index
  if (i >= (long)N * 32) return;
  int c4 = (int)(i & 31);
  long n = i >> 5;
  int g = batch[n];
  float4 v = ((const float4*)out)[i];
  float4 ms = ((const float4*)msub)[g * 32 + c4];
  float4 is = ((const float4*)istd)[g * 32 + c4];
  float4 w  = ((const float4*)gnw)[c4];
  float4 b  = ((const float4*)gnb)[c4];
  float4 o;
  o.x = fmaf(w.x * (v.x - ms.x), is.x, b.x);
  o.y = fmaf(w.y * (v.y - ms.y), is.y, b.y);
  o.z = fmaf(w.z * (v.z - ms.z), is.z, b.z);
  o.w = fmaf(w.w * (v.w - ms.w), is.w, b.w);
  o.x = o.x > 0.f ? o.x : expm1f(o.x);
  o.y = o.y > 0.f ? o.y : expm1f(o.y);
  o.z = o.z > 0.f ? o.z : expm1f(o.z);
  o.w = o.w > 0.f ? o.w : expm1f(o.w);
  ((float4*)out)[i] = o;
}

extern "C" void kernel_launch(void* const* d_in, const int* in_sizes, int n_in,
                              void* d_out, int out_size, void* d_ws, size_t ws_size,
                              hipStream_t stream) {
  const float* x    = (const float*)d_in[0];
  const int*   ei   = (const int*)d_in[1];
  const float* ea   = (const float*)d_in[2];
  const int*   batch= (const int*)d_in[3];
  const float* Wl   = (const float*)d_in[4];
  const float* bl   = (const float*)d_in[5];
  const float* Wr   = (const float*)d_in[6];
  const float* br   = (const float*)d_in[7];
  const float* We   = (const float*)d_in[8];
  const float* att  = (const float*)d_in[9];
  const float* bias = (const float*)d_in[10];
  const float* gnw  = (const float*)d_in[11];
  const float* gnb  = (const float*)d_in[12];
  const float* gms  = (const float*)d_in[13];
  int N = in_sizes[0] / HC;
  int E = in_sizes[2] / EDIM;
  float* out = (float*)d_out;
  (void)n_in; (void)out_size; (void)ws_size;

  // ---- workspace carve-up (4-byte words, 16B aligned blocks) ----
  float* wsf = (float*)d_ws;
  size_t off = 0;
  auto alloc = [&](size_t words) -> float* {
    float* p = wsf + off;
    off += (words + 3) & ~(size_t)3;
    return p;
  };
  int*      deg     = (int*)alloc(N);
  float*    gsum    = alloc(NG * HC);
  float*    gsq     = alloc(NG * HC);
  int*      genc    = (int*)alloc(NG);
  size_t zero_words = off;                 // everything above starts at 0
  int*      gstart  = (int*)alloc(NG + 1);
  float*    msub    = alloc(NG * HC);
  float*    istd    = alloc(NG * HC);
  int*      bsum    = (int*)alloc(256);
  int*      bofs    = (int*)alloc(256);
  int*      offsets = (int*)alloc((size_t)N + 1);
  float*    xl      = alloc((size_t)N * HC);
  float*    xr      = alloc((size_t)N * HC);
  int2*     csr2    = (int2*)alloc((size_t)E * 2);

  int nb = (N + 255) / 256;   // scan blocks (<=256 by construction for N<=65536)

  zero_k<<<(unsigned)((zero_words + 255) / 256), 256, 0, stream>>>(wsf, zero_words);
  count_deg_mark<<<(E + 255) / 256, 256, 0, stream>>>(ei, deg, batch, genc, E, N);
  gemm_tiled<<<(N + GEMM_ROWS - 1) / GEMM_ROWS, 256, 0, stream>>>(x, Wl, bl, Wr, br, xl, xr, N);
  scan1<<<nb, 256, 0, stream>>>(deg, bsum, N);
  scan2<<<1, 1, 0, stream>>>(bsum, bofs, nb, offsets, N, genc, gstart);
  scan3<<<nb, 256, 0, stream>>>(deg, bofs, offsets, N);
  fill_csr<<<(E + 255) / 256, 256, 0, stream>>>(ei, deg, offsets, csr2, E);
  fused_node<<<(N + 3) / 4, 256, 0, stream>>>(offsets, csr2, ea, xl, xr, We, att, x, bias, out, N);
  gn_stats<<<NG * GN_SLICES, 128, 0, stream>>>(out, gstart, gsum, gsq);
  gn_finalize<<<(NG * HC + 255) / 256, 256, 0, stream>>>(gsum, gsq, gstart, gms, msub, istd);
  {
    long tot = (long)N * 32;
    gn_apply<<<(unsigned)((tot + 255) / 256), 256, 0, stream>>>(out, batch, msub, istd, gnw, gnb, N);
  }
}

// Round 8
// 378.910 us; speedup vs baseline: 1.0593x; 1.0593x over previous
//
#include <hip/hip_runtime.h>

#define HC 128          // H*C = output dim
#define HEADS 8
#define CPH 16
#define EDIM 16
#define NG 8
#define GEPS 1e-5f
#define LOG2E 1.44269504f

typedef float f32x2 __attribute__((ext_vector_type(2)));

// ---------- 8-lane (head) sum via DPP: half_mirror + quad_perm xor2/xor1 ----------
__device__ __forceinline__ float head8_sum(float p) {
  int t;
  t = __builtin_amdgcn_update_dpp(0, __float_as_int(p), 0x141, 0xF, 0xF, true); // row_half_mirror
  p += __int_as_float(t);
  t = __builtin_amdgcn_update_dpp(0, __float_as_int(p), 0x4E, 0xF, 0xF, true);  // quad_perm [2,3,0,1]
  p += __int_as_float(t);
  t = __builtin_amdgcn_update_dpp(0, __float_as_int(p), 0xB1, 0xF, 0xF, true);  // quad_perm [1,0,3,2]
  p += __int_as_float(t);
  return p;
}

// ---------- K0: zero scratch ----------
__global__ void zero_k(float* __restrict__ p, size_t nwords) {
  size_t i = (size_t)blockIdx.x * 256 + threadIdx.x;
  if (i < nwords) p[i] = 0.f;
}

// ---------- K1: degree of real edges (by dst) + group-boundary marks ----------
__global__ void count_deg_mark(const int* __restrict__ ei, int* __restrict__ deg,
                               const int* __restrict__ batch, int* __restrict__ genc,
                               int E, int N) {
  int e = blockIdx.x * 256 + threadIdx.x;
  if (e >= E) return;
  atomicAdd(&deg[ei[E + e]], 1);
  if (e < N && (e == 0 || batch[e] != batch[e - 1])) {
    // encode start index i as (N - i) so zero-init means "empty group"
    atomicMax(&genc[batch[e]], N - e);
  }
}

// ---------- K2: xl = x@Wl+bl, xr = x@Wr+br — LDS-tiled GEMM, all-LDS inner loop ----
#define GEMM_ROWS 32
__global__ void __launch_bounds__(256) gemm_tiled(
    const float* __restrict__ x,
    const float* __restrict__ Wl, const float* __restrict__ bl,
    const float* __restrict__ Wr, const float* __restrict__ br,
    float* __restrict__ xl, float* __restrict__ xr, int N) {
  __shared__ float4 WL[32][32];   // [k within chunk][col float4 group] 16KB
  __shared__ float4 WR[32][32];   // 16KB
  __shared__ float4 XS[GEMM_ROWS][8];  // [local row][k4 within chunk] 4KB
  int t = threadIdx.x;
  int cg = t & 31;                // col float4 group (0..31)
  int rt = t >> 5;                // row-thread (0..7), owns rows rt*4..rt*4+3
  int row0 = blockIdx.x * GEMM_ROWS;
  float4 bl4 = ((const float4*)bl)[cg];
  float4 br4 = ((const float4*)br)[cg];
  float4 accl[4], accr[4];
  #pragma unroll
  for (int r = 0; r < 4; ++r) { accl[r] = bl4; accr[r] = br4; }
  const float4* Wl4 = (const float4*)Wl;
  const float4* Wr4 = (const float4*)Wr;
  const float4* x4  = (const float4*)x;
  int srow = t >> 3, sk4 = t & 7;
  long sgrow = row0 + srow;
  for (int kc = 0; kc < 4; ++kc) {
    __syncthreads();              // previous chunk fully consumed
    #pragma unroll
    for (int i = 0; i < 4; ++i) {
      int idx = t + i * 256;      // 0..1023
      int kr = idx >> 5, gg = idx & 31;
      WL[kr][gg] = Wl4[(kc * 32 + kr) * 32 + gg];
      WR[kr][gg] = Wr4[(kc * 32 + kr) * 32 + gg];
    }
    XS[srow][sk4] = (sgrow < N) ? x4[sgrow * 32 + kc * 8 + sk4]
                                : make_float4(0.f, 0.f, 0.f, 0.f);
    __syncthreads();
    #pragma unroll
    for (int k4 = 0; k4 < 8; ++k4) {
      float4 xv[4];
      #pragma unroll
      for (int r = 0; r < 4; ++r) xv[r] = XS[rt * 4 + r][k4];
      #pragma unroll
      for (int kk = 0; kk < 4; ++kk) {
        float4 wl = WL[k4 * 4 + kk][cg];
        float4 wr = WR[k4 * 4 + kk][cg];
        #pragma unroll
        for (int r = 0; r < 4; ++r) {
          float xs = (&xv[r].x)[kk];
          accl[r].x = fmaf(xs, wl.x, accl[r].x);
          accl[r].y = fmaf(xs, wl.y, accl[r].y);
          accl[r].z = fmaf(xs, wl.z, accl[r].z);
          accl[r].w = fmaf(xs, wl.w, accl[r].w);
          accr[r].x = fmaf(xs, wr.x, accr[r].x);
          accr[r].y = fmaf(xs, wr.y, accr[r].y);
          accr[r].z = fmaf(xs, wr.z, accr[r].z);
          accr[r].w = fmaf(xs, wr.w, accr[r].w);
        }
      }
    }
  }
  #pragma unroll
  for (int r = 0; r < 4; ++r) {
    long row = row0 + rt * 4 + r;
    if (row < N) {
      ((float4*)(xl + row * HC))[cg] = accl[r];
      ((float4*)(xr + row * HC))[cg] = accr[r];
    }
  }
}

// ---------- K3: scan of deg -> offsets (CSR) ----------
__global__ void scan1(const int* __restrict__ deg, int* __restrict__ bsum, int N) {
  __shared__ int s[256];
  int t = threadIdx.x;
  int n = blockIdx.x * 256 + t;
  s[t] = (n < N) ? deg[n] : 0;
  __syncthreads();
  for (int off = 128; off > 0; off >>= 1) {
    if (t < off) s[t] += s[t + off];
    __syncthreads();
  }
  if (t == 0) bsum[blockIdx.x] = s[0];
}
// parallel scan of block sums (nb <= 256) + group-start decode; 1 block x 256
__global__ void scan2(const int* __restrict__ bsum, int* __restrict__ bofs, int nb,
                      int* __restrict__ offsets, int N,
                      const int* __restrict__ genc, int* __restrict__ gstart) {
  __shared__ int s[256];
  int t = threadIdx.x;
  int v = (t < nb) ? bsum[t] : 0;
  s[t] = v;
  __syncthreads();
  for (int off = 1; off < 256; off <<= 1) {
    int add = (t >= off) ? s[t - off] : 0;
    __syncthreads();
    s[t] += add;
    __syncthreads();
  }
  if (t < nb) bofs[t] = s[t] - v;        // exclusive
  if (t == 255) offsets[N] = s[255];     // total (tail lanes contribute 0)
  if (t == 0) {
    // decode group starts; suffix-min so empty groups collapse to 0-length
    int nxt = N;
    gstart[NG] = N;
    for (int g = NG - 1; g >= 0; --g) {
      int st = N - genc[g];
      if (st > nxt) st = nxt;
      gstart[g] = st;
      nxt = st;
    }
  }
}
__global__ void scan3(const int* __restrict__ deg, const int* __restrict__ bofs,
                      int* __restrict__ offsets, int N) {
  __shared__ int s[256];
  int t = threadIdx.x;
  int n = blockIdx.x * 256 + t;
  int v = (n < N) ? deg[n] : 0;
  s[t] = v;
  __syncthreads();
  for (int off = 1; off < 256; off <<= 1) {
    int add = (t >= off) ? s[t - off] : 0;
    __syncthreads();
    s[t] += add;
    __syncthreads();
  }
  if (n < N) offsets[n] = bofs[blockIdx.x] + s[t] - v;  // exclusive
}

// ---------- K4: fill CSR with (edge, src) pairs; consumes deg ----------
__global__ void fill_csr(const int* __restrict__ ei, int* __restrict__ deg,
                         const int* __restrict__ offsets, int2* __restrict__ csr2, int E) {
  int e = blockIdx.x * 256 + threadIdx.x;
  if (e >= E) return;
  int d = ei[E + e];
  int pos = atomicSub(&deg[d], 1) - 1;
  csr2[offsets[d] + pos] = make_int2(e, ei[e]);
}

// ---------- K5: FUSED per-node attention + defer-max online softmax + agg ----------
// ONE WAVE per destination node; lane l owns channels (2l, 2l+1) as packed f32x2.
// Unroll-4 edge loop with one-quad-ahead INDEX PREFETCH: csr2 indices for quad
// i+1 load during quad i's compute, so the quad's 4 xl gathers + 16 ea loads
// issue back-to-back at iteration top (R7 lesson: 2-edge loop was latency-bound,
// VALUBusy 46%). Head = 8 lanes -> 3-stage DPP reduce. Self-loop (ea fill
// 'mean') merged at the end via linearity. Logits in log2 space.
__global__ void __launch_bounds__(256) fused_node(
    const int* __restrict__ offsets, const int2* __restrict__ csr2,
    const float* __restrict__ ea,
    const float* __restrict__ xl, const float* __restrict__ xr,
    const float* __restrict__ We, const float* __restrict__ att,
    const float* __restrict__ x, const float* __restrict__ bias,
    float* __restrict__ out, int N) {
  int l = threadIdx.x & 63;
  long n = (long)blockIdx.x * 4 + (threadIdx.x >> 6);
  if (n >= N) return;
  int c0 = l * 2;
  // We pairs, k-major: wx[kp] = (We[2kp][c0], We[2kp+1][c0]); wy for c0+1.
  f32x2 wx[8], wy[8];
  #pragma unroll
  for (int kp = 0; kp < 8; ++kp) {
    wx[kp] = (f32x2){We[(2 * kp) * HC + c0],     We[(2 * kp + 1) * HC + c0]};
    wy[kp] = (f32x2){We[(2 * kp) * HC + c0 + 1], We[(2 * kp + 1) * HC + c0 + 1]};
  }
  f32x2 av2 = {att[c0] * LOG2E, att[c0 + 1] * LOG2E};
  f32x2 av08 = 0.8f * av2, av02 = 0.2f * av2;
  f32x2 xl2 = *(const f32x2*)(xl + n * HC + c0);
  f32x2 xr2 = *(const f32x2*)(xr + n * HC + c0);
  f32x2 seedA = {xr2.x, 0.f};   // dot-accumulator seeds (fold +xr into hadd)
  f32x2 seedB = {xr2.y, 0.f};
  int j0 = offsets[n], j1 = offsets[n + 1];

  float m = -INFINITY;          // running max (log2), uniform per 8-lane head
  float den = 0.f;
  f32x2 acc = {0.f, 0.f};
  f32x2 eesum = {0.f, 0.f};     // per-channel sum of (eev + xr); adjusted at end

  auto edge_update = [&](int e, f32x2 xls) {
    const float4* eap = (const float4*)(ea + (long)e * EDIM);
    float4 a0 = eap[0], a1 = eap[1], a2 = eap[2], a3 = eap[3];
    f32x2 dA = seedA, dB = seedB;
    f32x2 e01;
    e01 = (f32x2){a0.x, a0.y};
    dA = __builtin_elementwise_fma(e01, wx[0], dA);
    dB = __builtin_elementwise_fma(e01, wy[0], dB);
    e01 = (f32x2){a0.z, a0.w};
    dA = __builtin_elementwise_fma(e01, wx[1], dA);
    dB = __builtin_elementwise_fma(e01, wy[1], dB);
    e01 = (f32x2){a1.x, a1.y};
    dA = __builtin_elementwise_fma(e01, wx[2], dA);
    dB = __builtin_elementwise_fma(e01, wy[2], dB);
    e01 = (f32x2){a1.z, a1.w};
    dA = __builtin_elementwise_fma(e01, wx[3], dA);
    dB = __builtin_elementwise_fma(e01, wy[3], dB);
    e01 = (f32x2){a2.x, a2.y};
    dA = __builtin_elementwise_fma(e01, wx[4], dA);
    dB = __builtin_elementwise_fma(e01, wy[4], dB);
    e01 = (f32x2){a2.z, a2.w};
    dA = __builtin_elementwise_fma(e01, wx[5], dA);
    dB = __builtin_elementwise_fma(e01, wy[5], dB);
    e01 = (f32x2){a3.x, a3.y};
    dA = __builtin_elementwise_fma(e01, wx[6], dA);
    dB = __builtin_elementwise_fma(e01, wy[6], dB);
    e01 = (f32x2){a3.z, a3.w};
    dA = __builtin_elementwise_fma(e01, wx[7], dA);
    dB = __builtin_elementwise_fma(e01, wy[7], dB);
    f32x2 mm = {dA.x + dA.y, dB.x + dB.y};   // = eev + xr (per channel)
    eesum += mm;
    mm += xls;
    f32x2 t = __builtin_elementwise_fma(
        av08, __builtin_elementwise_max(mm, (f32x2)0.f), av02 * mm);
    float p = head8_sum(t.x + t.y);    // head logit, uniform in 8-lane group
    if (p > m + 11.5f) {               // rare: new max grew past threshold
      float sc = exp2f(m - p);
      acc = acc * sc + xls;
      den = fmaf(den, sc, 1.f);
      m = p;
    } else {                           // common: single exp2, no rescale
      float w = exp2f(p - m);
      acc = __builtin_elementwise_fma((f32x2)w, xls, acc);
      den += w;
    }
  };

  auto edge_single = [&](int jj) {
    int2 es = csr2[jj];
    int e = __builtin_amdgcn_readfirstlane(es.x);
    int s = __builtin_amdgcn_readfirstlane(es.y);
    edge_update(e, *(const f32x2*)(xl + (long)s * HC + c0));
  };

  int j = j0;
  if ((j & 1) && j < j1) { edge_single(j); ++j; }   // peel to 16B alignment
  int nq = (j1 - j) >> 2;                           // full quads of 4 edges
  if (nq > 0) {
    int4 qa = *(const int4*)(csr2 + j);
    int4 qb = *(const int4*)(csr2 + j + 2);
    for (int q = 0; q < nq; ++q) {
      int4 qa2, qb2;
      bool more = (q + 1 < nq);
      if (more) {                      // prefetch next quad's indices NOW;
        qa2 = *(const int4*)(csr2 + j + 4);   // they arrive during compute
        qb2 = *(const int4*)(csr2 + j + 6);
      }
      int e0 = __builtin_amdgcn_readfirstlane(qa.x);
      int s0 = __builtin_amdgcn_readfirstlane(qa.y);
      int e1 = __builtin_amdgcn_readfirstlane(qa.z);
      int s1 = __builtin_amdgcn_readfirstlane(qa.w);
      int e2 = __builtin_amdgcn_readfirstlane(qb.x);
      int s2 = __builtin_amdgcn_readfirstlane(qb.y);
      int e3 = __builtin_amdgcn_readfirstlane(qb.z);
      int s3 = __builtin_amdgcn_readfirstlane(qb.w);
      f32x2 xls0 = *(const f32x2*)(xl + (long)s0 * HC + c0);   // 4 gathers
      f32x2 xls1 = *(const f32x2*)(xl + (long)s1 * HC + c0);   // issue together
      f32x2 xls2 = *(const f32x2*)(xl + (long)s2 * HC + c0);
      f32x2 xls3 = *(const f32x2*)(xl + (long)s3 * HC + c0);
      edge_update(e0, xls0);
      edge_update(e1, xls1);
      edge_update(e2, xls2);
      edge_update(e3, xls3);
      if (more) { qa = qa2; qb = qb2; }
      j += 4;
    }
  }
  for (; j < j1; ++j) edge_single(j);               // tail 0..3

  // ---- self-loop ----
  int dg = j1 - j0;
  f32x2 ee = (dg > 0) ? (eesum * (1.f / (float)dg) - xr2) : (f32x2)0.f;
  f32x2 mm = xl2 + xr2 + ee;
  f32x2 t = __builtin_elementwise_fma(
      av08, __builtin_elementwise_max(mm, (f32x2)0.f), av02 * mm);
  float p = head8_sum(t.x + t.y);
  if (p > m) {
    float sc = exp2f(m - p);
    acc = acc * sc + xl2;
    den = fmaf(den, sc, 1.f);
  } else {
    float w = exp2f(p - m);
    acc = __builtin_elementwise_fma((f32x2)w, xl2, acc);
    den += w;
  }

  f32x2 b2 = *(const f32x2*)(bias + c0);
  f32x2 x2 = *(const f32x2*)(x + n * HC + c0);
  f32x2 o = acc * (1.f / den) + b2 + x2;
  *(f32x2*)(out + n * HC + c0) = o;
}

// ---------- K6: GraphNorm segment sums (grid-parallel over group slices) ----------
#define GN_SLICES 32
__global__ void __launch_bounds__(128) gn_stats(
    const float* __restrict__ out, const int* __restrict__ gstart,
    float* __restrict__ gsum, float* __restrict__ gsq) {
  int g = blockIdx.x >> 5;
  int slice = blockIdx.x & 31;
  int s0 = gstart[g], s1 = gstart[g + 1];
  int cnt = s1 - s0;
  if (cnt <= 0) return;
  int chunk = (cnt + GN_SLICES - 1) / GN_SLICES;
  int lo = s0 + slice * chunk;
  int hi = lo + chunk; if (hi > s1) hi = s1;
  if (lo >= hi) return;
  int ch = threadIdx.x;
  float sum = 0.f, sq = 0.f;
  for (int nrow = lo; nrow < hi; ++nrow) {
    float v = out[(long)nrow * HC + ch];
    sum += v; sq += v * v;
  }
  atomicAdd(&gsum[g * HC + ch], sum);
  atomicAdd(&gsq[g * HC + ch], sq);
}

// ---------- K7: finalize mean / inv-std ----------
__global__ void gn_finalize(const float* __restrict__ gsum, const float* __restrict__ gsq,
                            const int* __restrict__ gstart, const float* __restrict__ gms,
                            float* __restrict__ msub, float* __restrict__ istd) {
  int t = blockIdx.x * 256 + threadIdx.x;
  if (t >= NG * HC) return;
  int g = t >> 7, ch = t & 127;
  float cnt = (float)(gstart[g + 1] - gstart[g]);
  if (cnt < 1.f) cnt = 1.f;
  float mean = gsum[t] / cnt;
  float c = gms[ch] * mean;              // the subtracted constant
  float ex2 = gsq[t] / cnt;
  float var = ex2 - 2.f * c * mean + c * c;   // E[(x-c)^2]
  msub[t] = c;
  istd[t] = rsqrtf(var + GEPS);
}

// ---------- K8: normalize + affine + ELU (float4) ----------
__global__ void gn_apply(float* __restrict__ out, const int* __restrict__ batch,
                         const float* __restrict__ msub, const float* __restrict__ istd,
                         const float* __restrict__ gnw, const float* __restrict__ gnb, int N) {
  long i = (long)blockIdx.x * 256 + threadIdx.x;     // float4 index
  if (i >= (long)N * 32) return;
  int c4 = (int)(i & 31);
  long n = i >> 5;
  int g = batch[n];
  float4 v = ((const float4*)out)[i];
  float4 ms = ((const float4*)msub)[g * 32 + c4];
  float4 is = ((const float4*)istd)[g * 32 + c4];
  float4 w  = ((const float4*)gnw)[c4];
  float4 b  = ((const float4*)gnb)[c4];
  float4 o;
  o.x = fmaf(w.x * (v.x - ms.x), is.x, b.x);
  o.y = fmaf(w.y * (v.y - ms.y), is.y, b.y);
  o.z = fmaf(w.z * (v.z - ms.z), is.z, b.z);
  o.w = fmaf(w.w * (v.w - ms.w), is.w, b.w);
  o.x = o.x > 0.f ? o.x : expm1f(o.x);
  o.y = o.y > 0.f ? o.y : expm1f(o.y);
  o.z = o.z > 0.f ? o.z : expm1f(o.z);
  o.w = o.w > 0.f ? o.w : expm1f(o.w);
  ((float4*)out)[i] = o;
}

extern "C" void kernel_launch(void* const* d_in, const int* in_sizes, int n_in,
                              void* d_out, int out_size, void* d_ws, size_t ws_size,
                              hipStream_t stream) {
  const float* x    = (const float*)d_in[0];
  const int*   ei   = (const int*)d_in[1];
  const float* ea   = (const float*)d_in[2];
  const int*   batch= (const int*)d_in[3];
  const float* Wl   = (const float*)d_in[4];
  const float* bl   = (const float*)d_in[5];
  const float* Wr   = (const float*)d_in[6];
  const float* br   = (const float*)d_in[7];
  const float* We   = (const float*)d_in[8];
  const float* att  = (const float*)d_in[9];
  const float* bias = (const float*)d_in[10];
  const float* gnw  = (const float*)d_in[11];
  const float* gnb  = (const float*)d_in[12];
  const float* gms  = (const float*)d_in[13];
  int N = in_sizes[0] / HC;
  int E = in_sizes[2] / EDIM;
  float* out = (float*)d_out;
  (void)n_in; (void)out_size; (void)ws_size;

  // ---- workspace carve-up (4-byte words, 16B aligned blocks) ----
  float* wsf = (float*)d_ws;
  size_t off = 0;
  auto alloc = [&](size_t words) -> float* {
    float* p = wsf + off;
    off += (words + 3) & ~(size_t)3;
    return p;
  };
  int*      deg     = (int*)alloc(N);
  float*    gsum    = alloc(NG * HC);
  float*    gsq     = alloc(NG * HC);
  int*      genc    = (int*)alloc(NG);
  size_t zero_words = off;                 // everything above starts at 0
  int*      gstart  = (int*)alloc(NG + 1);
  float*    msub    = alloc(NG * HC);
  float*    istd    = alloc(NG * HC);
  int*      bsum    = (int*)alloc(256);
  int*      bofs    = (int*)alloc(256);
  int*      offsets = (int*)alloc((size_t)N + 1);
  float*    xl      = alloc((size_t)N * HC);
  float*    xr      = alloc((size_t)N * HC);
  int2*     csr2    = (int2*)alloc((size_t)E * 2 + 8);  // +8 pad for prefetch

  int nb = (N + 255) / 256;   // scan blocks (<=256 by construction for N<=65536)

  zero_k<<<(unsigned)((zero_words + 255) / 256), 256, 0, stream>>>(wsf, zero_words);
  count_deg_mark<<<(E + 255) / 256, 256, 0, stream>>>(ei, deg, batch, genc, E, N);
  gemm_tiled<<<(N + GEMM_ROWS - 1) / GEMM_ROWS, 256, 0, stream>>>(x, Wl, bl, Wr, br, xl, xr, N);
  scan1<<<nb, 256, 0, stream>>>(deg, bsum, N);
  scan2<<<1, 256, 0, stream>>>(bsum, bofs, nb, offsets, N, genc, gstart);
  scan3<<<nb, 256, 0, stream>>>(deg, bofs, offsets, N);
  fill_csr<<<(E + 255) / 256, 256, 0, stream>>>(ei, deg, offsets, csr2, E);
  fused_node<<<(N + 3) / 4, 256, 0, stream>>>(offsets, csr2, ea, xl, xr, We, att, x, bias, out, N);
  gn_stats<<<NG * GN_SLICES, 128, 0, stream>>>(out, gstart, gsum, gsq);
  gn_finalize<<<(NG * HC + 255) / 256, 256, 0, stream>>>(gsum, gsq, gstart, gms, msub, istd);
  {
    long tot = (long)N * 32;
    gn_apply<<<(unsigned)((tot + 255) / 256), 256, 0, stream>>>(out, batch, msub, istd, gnw, gnb, N);
  }
}